// Round 1
// baseline (143.161 us; speedup 1.0000x reference)
//
#include <hip/hip_runtime.h>

#define NN    16384
#define CBN   64
#define SUBV  16
#define KCODE 16
#define DOUTN 1024
#define DEP   4

typedef short bf16x8 __attribute__((ext_vector_type(8)));
typedef float f32x16 __attribute__((ext_vector_type(16)));

static __device__ __forceinline__ unsigned short f2bf(float f) {
  unsigned int u = __float_as_uint(f);
  u += 0x7FFFu + ((u >> 16) & 1u);   // RNE; inputs are normal randn, no NaN/Inf
  return (unsigned short)(u >> 16);
}

// ---------------- kernel 1: encode ----------------
// 256 threads handle 8 rows of x. Codes written transposed: codes[c][n] (u8).
__global__ __launch_bounds__(256) void encode_k(
    const float* __restrict__ x, const int* __restrict__ split_idxs,
    const float* __restrict__ split_vals, unsigned char* __restrict__ codes) {
  __shared__ float xs[8][DOUTN + 1];          // +1 pad: breaks LDS bank aliasing
  __shared__ int   sidx[CBN * DEP];
  __shared__ float sval[CBN * DEP * (KCODE / 2)];
  const int t = threadIdx.x;
  if (t < CBN * DEP) sidx[t] = split_idxs[t];
  for (int i = t; i < CBN * DEP * (KCODE / 2); i += 256) sval[i] = split_vals[i];
  const int n0 = blockIdx.x * 8;
  const float4* xg = (const float4*)(x + (size_t)n0 * DOUTN);
  #pragma unroll
  for (int i = 0; i < 8; ++i) {                // 8 rows * 256 float4/row
    int li = t + i * 256;
    int r = li >> 8, cpos = li & 255;
    float4 v = xg[r * 256 + cpos];
    xs[r][cpos * 4 + 0] = v.x; xs[r][cpos * 4 + 1] = v.y;
    xs[r][cpos * 4 + 2] = v.z; xs[r][cpos * 4 + 3] = v.w;
  }
  __syncthreads();
  const int c = t >> 2;                        // 64 codebooks
  unsigned int pk = 0;
  #pragma unroll
  for (int i = 0; i < 2; ++i) {
    int nl = (t & 3) * 2 + i;                  // 8 local rows
    int e = 0;
    #pragma unroll
    for (int d = 0; d < DEP; ++d) {
      float xv = xs[nl][c * SUBV + sidx[c * DEP + d]];
      float th = sval[(c * DEP + d) * (KCODE / 2) + e];
      e = 2 * e + (xv > th ? 1 : 0);
    }
    pk |= ((unsigned int)e) << (8 * i);
  }
  *(unsigned short*)(codes + (size_t)c * NN + n0 + (t & 3) * 2) = (unsigned short)pk;
}

// ---------------- kernel 2: one-hot MFMA gather-accumulate ----------------
// grid (8 colgroups, 64 rowgroups); block = 256 thr = 4 waves.
// Block: 256 rows x 128 cols. Wave w: rows [w*64, w*64+64) (2 row-tiles of 32),
// all 4 col-tiles of 32. Per codebook c: acc += onehot(code) @ T[c] via
// v_mfma_f32_32x32x16_bf16. k-slot labeling is consistent between the A
// (identity-row read) and B (Tb[c][col][k]) fragments, so the HW k-mapping
// cancels; relies only on A-row = B-col = lane&31 + measured C/D layout.
__global__ __launch_bounds__(256) void maddness_mfma(
    const float* __restrict__ Tg, const float* __restrict__ bias,
    const unsigned char* __restrict__ codes, float* __restrict__ out) {
  __shared__ __align__(16) unsigned short Tb[8][128][16];   // 32 KiB, [c][col][k]
  __shared__ __align__(16) unsigned char  cds[8][256];      // 2 KiB,  [c][row]
  __shared__ __align__(16) unsigned short Ident[16][16];    // 512 B one-hot rows

  const int t = threadIdx.x;
  const int w = t >> 6, lane = t & 63, lrow = lane & 31, h = lane >> 5;
  const int col0 = blockIdx.x * 128;
  const int n0   = blockIdx.y * 256;

  // bf16(1.0) = 0x3F80
  Ident[t >> 4][t & 15] = ((t >> 4) == (t & 15)) ? (unsigned short)0x3F80
                                                 : (unsigned short)0;

  f32x16 acc[2][4];
  #pragma unroll
  for (int a = 0; a < 2; ++a)
    #pragma unroll
    for (int b = 0; b < 4; ++b)
      #pragma unroll
      for (int e = 0; e < 16; ++e) acc[a][b][e] = 0.f;

  for (int ch = 0; ch < 8; ++ch) {
    if (ch) __syncthreads();                   // previous chunk's compute done
    // stage codes for this c-chunk: 8 c * 256 rows, u64 per thread
    ((unsigned long long*)cds)[t] =
        *(const unsigned long long*)(codes + (size_t)(ch * 8 + (t >> 5)) * NN
                                     + n0 + (t & 31) * 8);
    // stage table chunk: 8 c * 16 k * 128 cols f32 -> bf16, k-fastest in LDS
    #pragma unroll
    for (int i = 0; i < 8; ++i) {
      int idx = t + i * 256;                   // 2048 items = (c, kpair, colq)
      int colq = idx & 31, kp = (idx >> 5) & 7, cl = idx >> 8;
      const float* g0 = Tg + ((size_t)(ch * 8 + cl) * KCODE + 2 * kp) * DOUTN
                        + col0 + colq * 4;
      float4 r0 = *(const float4*)g0;          // row k=2kp, 4 cols (coalesced)
      float4 r1 = *(const float4*)(g0 + DOUTN);// row k=2kp+1
      unsigned int p0 = f2bf(r0.x) | ((unsigned int)f2bf(r1.x) << 16);
      unsigned int p1 = f2bf(r0.y) | ((unsigned int)f2bf(r1.y) << 16);
      unsigned int p2 = f2bf(r0.z) | ((unsigned int)f2bf(r1.z) << 16);
      unsigned int p3 = f2bf(r0.w) | ((unsigned int)f2bf(r1.w) << 16);
      *(unsigned int*)&Tb[cl][colq * 4 + 0][2 * kp] = p0;
      *(unsigned int*)&Tb[cl][colq * 4 + 1][2 * kp] = p1;
      *(unsigned int*)&Tb[cl][colq * 4 + 2][2 * kp] = p2;
      *(unsigned int*)&Tb[cl][colq * 4 + 3][2 * kp] = p3;
    }
    __syncthreads();
    #pragma unroll
    for (int cl = 0; cl < 8; ++cl) {
      int code0 = cds[cl][w * 64 + lrow];
      int code1 = cds[cl][w * 64 + 32 + lrow];
      bf16x8 a0 = *(const bf16x8*)&Ident[code0][h * 8];   // one-hot, k-half h
      bf16x8 a1 = *(const bf16x8*)&Ident[code1][h * 8];
      #pragma unroll
      for (int ct = 0; ct < 4; ++ct) {
        bf16x8 bv = *(const bf16x8*)&Tb[cl][ct * 32 + lrow][h * 8]; // b128, conflict-free
        acc[0][ct] = __builtin_amdgcn_mfma_f32_32x32x16_bf16(a0, bv, acc[0][ct], 0, 0, 0);
        acc[1][ct] = __builtin_amdgcn_mfma_f32_32x32x16_bf16(a1, bv, acc[1][ct], 0, 0, 0);
      }
    }
  }

  // epilogue: D layout col=lane&31, row=(reg&3)+8*(reg>>2)+4*(lane>>5)
  float bv[4];
  #pragma unroll
  for (int ct = 0; ct < 4; ++ct) bv[ct] = bias[col0 + ct * 32 + lrow];
  #pragma unroll
  for (int rt = 0; rt < 2; ++rt)
    #pragma unroll
    for (int ct = 0; ct < 4; ++ct) {
      int col = col0 + ct * 32 + lrow;
      #pragma unroll
      for (int r = 0; r < 16; ++r) {
        int row = n0 + w * 64 + rt * 32 + (r & 3) + 8 * (r >> 2) + 4 * h;
        out[(size_t)row * DOUTN + col] = acc[rt][ct][r] + bv[ct];
      }
    }
}

extern "C" void kernel_launch(void* const* d_in, const int* in_sizes, int n_in,
                              void* d_out, int out_size, void* d_ws, size_t ws_size,
                              hipStream_t stream) {
  const float* x    = (const float*)d_in[0];
  const int*   sidx = (const int*)d_in[1];
  const float* sval = (const float*)d_in[2];
  const float* Tg   = (const float*)d_in[3];
  const float* bias = (const float*)d_in[4];
  float* out = (float*)d_out;
  unsigned char* codes = (unsigned char*)d_ws;   // 1 MiB: codes[c][n]

  encode_k<<<NN / 8, 256, 0, stream>>>(x, sidx, sval, codes);
  maddness_mfma<<<dim3(8, 64), 256, 0, stream>>>(Tg, bias, codes, out);
}

// Round 2
// 67.246 us; speedup vs baseline: 2.1289x; 2.1289x over previous
//
#include <hip/hip_runtime.h>

#define NN    16384
#define CBN   64
#define SUBV  16
#define KCODE 16
#define DOUTN 1024
#define DEP   4

typedef short bf16x8 __attribute__((ext_vector_type(8)));
typedef float f32x16 __attribute__((ext_vector_type(16)));

static __device__ __forceinline__ unsigned short f2bf(float f) {
  unsigned int u = __float_as_uint(f);
  u += 0x7FFFu + ((u >> 16) & 1u);   // RNE; inputs are normal randn, no NaN/Inf
  return (unsigned short)(u >> 16);
}

// ---------------- kernel 1: encode ----------------
// 256 threads, 8 rows of x per block. Codes written n-major: codes[n*64 + c]
// so kernel 2 reads a row's 8 chunk-codes as one u64.
__global__ __launch_bounds__(256) void encode_k(
    const float* __restrict__ x, const int* __restrict__ split_idxs,
    const float* __restrict__ split_vals, unsigned char* __restrict__ codes) {
  __shared__ float xs[8][DOUTN + 1];
  __shared__ int   sidxT[DEP * CBN];               // [d][c]  (bank = c&31, conflict-free)
  __shared__ float svalT[DEP * (KCODE / 2) * CBN]; // [d][e][c] (bank = c&31)
  const int t = threadIdx.x;
  if (t < DEP * CBN) {
    int d = t >> 6, c = t & 63;
    sidxT[t] = split_idxs[c * DEP + d];
  }
  for (int i = t; i < DEP * (KCODE / 2) * CBN; i += 256) {
    int c = i & 63, de = i >> 6, d = de >> 3, e = de & 7;
    svalT[i] = split_vals[(c * DEP + d) * (KCODE / 2) + e];
  }
  const int n0 = blockIdx.x * 8;
  const float4* xg = (const float4*)(x + (size_t)n0 * DOUTN);
  #pragma unroll
  for (int i = 0; i < 8; ++i) {                    // 8 rows * 256 float4/row
    int li = t + i * 256;
    int r = li >> 8, cpos = li & 255;
    float4 v = xg[r * 256 + cpos];
    xs[r][cpos * 4 + 0] = v.x; xs[r][cpos * 4 + 1] = v.y;
    xs[r][cpos * 4 + 2] = v.z; xs[r][cpos * 4 + 3] = v.w;
  }
  __syncthreads();
  const int c = t & 63, rg = t >> 6;               // lane = c -> coalesced u8 writes
  #pragma unroll
  for (int i = 0; i < 2; ++i) {
    int nl = rg * 2 + i;
    int e = 0;
    #pragma unroll
    for (int d = 0; d < DEP; ++d) {
      float xv = xs[nl][c * SUBV + sidxT[d * 64 + c]];
      float th = svalT[(d * 8 + e) * 64 + c];
      e = 2 * e + (xv > th ? 1 : 0);
    }
    codes[(size_t)(n0 + nl) * CBN + c] = (unsigned char)e;
  }
}

// ---------------- kernel 2: one-hot MFMA gather-accumulate ----------------
// grid (8 colgroups, 64 rowgroups); block = 512 thr = 8 waves.
// Block: 256 rows x 128 cols. Wave wid: rq = wid&3 (64-row quad), cq = wid>>2
// (64-col half); per wave 2 row-tiles x 2 col-tiles of 32.
// Tb is XOR-swizzled (byte bits[6:4] ^= (col>>2)&7) on BOTH write and read:
// kills the 8-way ds_read_b128 bank conflict of the linear [col][16] layout.
// A fragments are one-hot rows built in registers (VALU was idle; the LDS
// Ident gather was conflict-heavy). k-slot labeling stays consistent between
// A (a[h*8+j] = code==h*8+j) and B (Tb[col][h*8+j]), so HW k-mapping cancels.
__global__ __launch_bounds__(512, 4) void maddness_mfma(
    const float* __restrict__ Tg, const float* __restrict__ bias,
    const unsigned char* __restrict__ codes, float* __restrict__ out) {
  __shared__ __align__(16) unsigned short Tb[8 * 128 * KCODE];  // 32 KiB, swizzled

  const int t = threadIdx.x;
  const int wid = t >> 6, lane = t & 63, lrow = lane & 31, h = lane >> 5;
  const int rq = wid & 3, cq = wid >> 2;
  const int col0 = blockIdx.x * 128;
  const int n0   = blockIdx.y * 256;

  f32x16 acc[2][2];
  #pragma unroll
  for (int a = 0; a < 2; ++a)
    #pragma unroll
    for (int b = 0; b < 2; ++b)
      #pragma unroll
      for (int e = 0; e < 16; ++e) acc[a][b][e] = 0.f;

  for (int ch = 0; ch < 8; ++ch) {
    if (ch) __syncthreads();                 // previous chunk's reads done
    // stage table chunk: 8 c * 16 k * 128 cols f32 -> bf16, swizzled u32 writes
    #pragma unroll
    for (int i = 0; i < 4; ++i) {
      int idx = t + i * 512;                 // 2048 items = (cl, kp, colq)
      int colq = idx & 31, kp = (idx >> 5) & 7, cl = idx >> 8;
      const float* g0 = Tg + ((size_t)((ch * 8 + cl) * KCODE + 2 * kp)) * DOUTN
                        + col0 + colq * 4;
      float4 r0 = *(const float4*)g0;        // k=2kp, 4 cols (coalesced)
      float4 r1 = *(const float4*)(g0 + DOUTN);
      unsigned int pk[4] = {
        f2bf(r0.x) | ((unsigned int)f2bf(r1.x) << 16),
        f2bf(r0.y) | ((unsigned int)f2bf(r1.y) << 16),
        f2bf(r0.z) | ((unsigned int)f2bf(r1.z) << 16),
        f2bf(r0.w) | ((unsigned int)f2bf(r1.w) << 16)};
      unsigned key = (unsigned)(colq & 7) << 2;      // XOR on u32-idx bits[4:2]
      #pragma unroll
      for (int j = 0; j < 4; ++j) {
        unsigned widx = (unsigned)(cl * 1024)
                      + ((((unsigned)(colq * 4 + j) * 8) + (unsigned)kp) ^ key);
        ((unsigned int*)Tb)[widx] = pk[j];
      }
    }
    // this wave's codes for the chunk: one u64 per row-tile (global, L1/L2-hot)
    unsigned long long qw0 = *(const unsigned long long*)(
        codes + (size_t)(n0 + rq * 64 + lrow) * CBN + ch * 8);
    unsigned long long qw1 = *(const unsigned long long*)(
        codes + (size_t)(n0 + rq * 64 + 32 + lrow) * CBN + ch * 8);
    __syncthreads();
    #pragma unroll
    for (int cl = 0; cl < 8; ++cl) {
      int c0 = (int)(qw0 >> (8 * cl)) & 255;
      int c1 = (int)(qw1 >> (8 * cl)) & 255;
      union { unsigned int u[4]; bf16x8 v; } A0, A1;
      unsigned s0 = 0x3F80u << ((c0 & 1) << 4);      // bf16(1.0) in right half
      unsigned s1 = 0x3F80u << ((c1 & 1) << 4);
      int p0 = c0 >> 1, p1 = c1 >> 1;
      #pragma unroll
      for (int j = 0; j < 4; ++j) {
        A0.u[j] = (p0 == h * 4 + j) ? s0 : 0u;
        A1.u[j] = (p1 == h * 4 + j) ? s1 : 0u;
      }
      #pragma unroll
      for (int ct = 0; ct < 2; ++ct) {
        int col = cq * 64 + ct * 32 + lrow;
        unsigned uidx = (unsigned)(cl * 2048)
                      + (((unsigned)(col * 16 + h * 8))
                         ^ ((((unsigned)col >> 2) & 7u) << 3));
        bf16x8 bv = *(const bf16x8*)(Tb + uidx);     // swizzled, conflict-free
        acc[0][ct] = __builtin_amdgcn_mfma_f32_32x32x16_bf16(A0.v, bv, acc[0][ct], 0, 0, 0);
        acc[1][ct] = __builtin_amdgcn_mfma_f32_32x32x16_bf16(A1.v, bv, acc[1][ct], 0, 0, 0);
      }
    }
  }

  // epilogue: D layout col=lane&31, row=(reg&3)+8*(reg>>2)+4*(lane>>5)
  float bval[2];
  #pragma unroll
  for (int ct = 0; ct < 2; ++ct) bval[ct] = bias[col0 + cq * 64 + ct * 32 + lrow];
  #pragma unroll
  for (int rt = 0; rt < 2; ++rt)
    #pragma unroll
    for (int ct = 0; ct < 2; ++ct) {
      int col = col0 + cq * 64 + ct * 32 + lrow;
      #pragma unroll
      for (int r = 0; r < 16; ++r) {
        int row = n0 + rq * 64 + rt * 32 + (r & 3) + 8 * (r >> 2) + 4 * h;
        out[(size_t)row * DOUTN + col] = acc[rt][ct][r] + bval[ct];
      }
    }
}

extern "C" void kernel_launch(void* const* d_in, const int* in_sizes, int n_in,
                              void* d_out, int out_size, void* d_ws, size_t ws_size,
                              hipStream_t stream) {
  const float* x    = (const float*)d_in[0];
  const int*   sidx = (const int*)d_in[1];
  const float* sval = (const float*)d_in[2];
  const float* Tg   = (const float*)d_in[3];
  const float* bias = (const float*)d_in[4];
  float* out = (float*)d_out;
  unsigned char* codes = (unsigned char*)d_ws;   // 1 MiB: codes[n][c]

  encode_k<<<NN / 8, 256, 0, stream>>>(x, sidx, sval, codes);
  maddness_mfma<<<dim3(8, 64), 512, 0, stream>>>(Tg, bias, codes, out);
}

// Round 3
// 59.135 us; speedup vs baseline: 2.4209x; 1.1372x over previous
//
#include <hip/hip_runtime.h>

#define NN    16384
#define CBN   64
#define SUBV  16
#define KCODE 16
#define DOUTN 1024
#define DEP   4

typedef short bf16x8 __attribute__((ext_vector_type(8)));
typedef float f32x16 __attribute__((ext_vector_type(16)));

static __device__ __forceinline__ unsigned short f2bf(float f) {
  unsigned int u = __float_as_uint(f);
  u += 0x7FFFu + ((u >> 16) & 1u);   // RNE; inputs are normal randn, no NaN/Inf
  return (unsigned short)(u >> 16);
}

// global -> LDS direct copy, 16B per lane. LDS dest must be wave-uniform;
// HW adds lane*16. Global src is per-lane.
static __device__ __forceinline__ void gld16(const void* g, void* l) {
  __builtin_amdgcn_global_load_lds(
      (const __attribute__((address_space(1))) unsigned int*)g,
      (__attribute__((address_space(3))) unsigned int*)(uintptr_t)l, 16, 0, 0);
}

// ---------------- kernel 1: encode + table convert/swizzle (fused) ----------
// blocks [0, 2048): encode 8 rows each -> codes[n][c] (u8, n-major).
// blocks [2048, 2112): build Tswz = bf16 table, pre-swizzled into the exact
// 32 KiB-per-(colgroup,chunk) LDS image kernel 2 stages linearly (rule #21).
__global__ __launch_bounds__(256) void prep_k(
    const float* __restrict__ x, const int* __restrict__ split_idxs,
    const float* __restrict__ split_vals, const float* __restrict__ Tg,
    unsigned char* __restrict__ codes, unsigned int* __restrict__ Tswz) {
  const int t = threadIdx.x;

  if (blockIdx.x >= NN / 8) {
    // ---- convert + swizzle: one block per (g, ch) image ----
    const int img = blockIdx.x - NN / 8;          // = g*8 + ch
    const int g = img >> 3, ch = img & 7;
    unsigned int* dst = Tswz + (size_t)img * 8192; // 8192 u32 = 32 KiB image
    const int colq = t & 31, kp = (t >> 5) & 7;   // per-thread (colq, kp)
    #pragma unroll
    for (int cl = 0; cl < 8; ++cl) {
      const float* g0 = Tg + ((size_t)((ch * 8 + cl) * KCODE + 2 * kp)) * DOUTN
                        + g * 128 + colq * 4;
      float4 r0 = *(const float4*)g0;             // k=2kp   (coalesced)
      float4 r1 = *(const float4*)(g0 + DOUTN);   // k=2kp+1
      unsigned int pk[4] = {
        f2bf(r0.x) | ((unsigned int)f2bf(r1.x) << 16),
        f2bf(r0.y) | ((unsigned int)f2bf(r1.y) << 16),
        f2bf(r0.z) | ((unsigned int)f2bf(r1.z) << 16),
        f2bf(r0.w) | ((unsigned int)f2bf(r1.w) << 16)};
      unsigned key = (unsigned)(colq & 7) << 2;   // XOR on u32-idx bits[4:2]
      #pragma unroll
      for (int j = 0; j < 4; ++j)
        dst[cl * 1024 + ((((unsigned)(colq * 4 + j)) * 8 + (unsigned)kp) ^ key)]
            = pk[j];
    }
    return;
  }

  // ---- encode ----
  __shared__ float xs[8][SUBV * CBN + CBN];        // addr = c*17 + s (anti-conflict)
  __shared__ int   sidxT[DEP * CBN];               // [d][c]
  __shared__ float svalT[DEP * (KCODE / 2) * CBN]; // [d][e][c]
  if (t < DEP * CBN) {
    int d = t >> 6, c = t & 63;
    sidxT[t] = split_idxs[c * DEP + d];
  }
  for (int i = t; i < DEP * (KCODE / 2) * CBN; i += 256) {
    int c = i & 63, de = i >> 6, d = de >> 3, e = de & 7;
    svalT[i] = split_vals[(c * DEP + d) * (KCODE / 2) + e];
  }
  const int n0 = blockIdx.x * 8;
  const float4* xg = (const float4*)(x + (size_t)n0 * DOUTN);
  #pragma unroll
  for (int i = 0; i < 8; ++i) {                    // 8 rows * 256 float4/row
    int li = t + i * 256;
    int r = li >> 8, cpos = li & 255;
    float4 v = xg[r * 256 + cpos];
    float* row = &xs[r][(cpos >> 2) * 17 + (cpos & 3) * 4];
    row[0] = v.x; row[1] = v.y; row[2] = v.z; row[3] = v.w;
  }
  __syncthreads();
  const int c = t & 63, rg = t >> 6;               // lane = c -> coalesced writes
  #pragma unroll
  for (int i = 0; i < 2; ++i) {
    int nl = rg * 2 + i;
    int e = 0;
    #pragma unroll
    for (int d = 0; d < DEP; ++d) {
      float xv = xs[nl][c * 17 + sidxT[d * 64 + c]];
      float th = svalT[(d * 8 + e) * 64 + c];
      e = 2 * e + (xv > th ? 1 : 0);
    }
    codes[(size_t)(n0 + nl) * CBN + c] = (unsigned char)e;
  }
}

// ---------------- kernel 2: one-hot MFMA gather-accumulate ----------------
// grid (8 colgroups, 128 rowgroups) = 1024 blocks; 256 thr = 4 waves;
// 2 blocks/CU (64 KiB LDS dbuf) -> 2 occupancy rounds so round-2 compute
// overlaps round-1's HBM write tail. Block: 128 rows x 128 cols; wave wid:
// rq=wid&1 (64-row half), cq=wid>>1 (64-col half). Staging is pure
// global_load_lds (no VALU, no LDS-write conflicts) from the pre-swizzled
// Tswz image; reads use the same XOR swizzle as R1 (verified layout).
__global__ __launch_bounds__(256, 2) void maddness_mfma(
    const unsigned int* __restrict__ Tswz, const float* __restrict__ bias,
    const unsigned char* __restrict__ codes, float* __restrict__ out) {
  __shared__ __align__(16) unsigned int Tb[2][8192];   // 2 x 32 KiB

  const int t = threadIdx.x;
  const int wid = t >> 6, lane = t & 63, lrow = lane & 31, h = lane >> 5;
  const int rq = wid & 1, cq = wid >> 1;
  const int g = blockIdx.x;
  const int n0 = blockIdx.y * 128;
  const char* imgs = (const char*)(Tswz + (size_t)g * 8 * 8192);

  // prologue: stage chunk 0 (linear 16B/lane copies; image is pre-swizzled)
  #pragma unroll
  for (int i = 0; i < 8; ++i)
    gld16(imgs + (wid * 8 + i) * 1024 + lane * 16,
          (char*)&Tb[0][0] + (wid * 8 + i) * 1024);

  // prefetch this wave's codes for ALL 8 chunks (static-indexed after unroll)
  ulonglong2 q0[4], q1[4];
  {
    const ulonglong2* cp0 = (const ulonglong2*)(codes + (size_t)(n0 + rq * 64 + lrow) * CBN);
    const ulonglong2* cp1 = (const ulonglong2*)(codes + (size_t)(n0 + rq * 64 + 32 + lrow) * CBN);
    #pragma unroll
    for (int i = 0; i < 4; ++i) { q0[i] = cp0[i]; q1[i] = cp1[i]; }
  }

  f32x16 acc[2][2];
  #pragma unroll
  for (int a = 0; a < 2; ++a)
    #pragma unroll
    for (int b = 0; b < 2; ++b)
      #pragma unroll
      for (int e = 0; e < 16; ++e) acc[a][b][e] = 0.f;

  __syncthreads();                                  // chunk 0 staged

  #pragma unroll
  for (int ch = 0; ch < 8; ++ch) {
    const int buf = ch & 1;
    if (ch < 7) {                                   // stage next chunk into buf^1
      const char* src = imgs + (ch + 1) * 32768;
      #pragma unroll
      for (int i = 0; i < 8; ++i)
        gld16(src + (wid * 8 + i) * 1024 + lane * 16,
              (char*)&Tb[buf ^ 1][0] + (wid * 8 + i) * 1024);
    }
    unsigned long long qw0 = (ch & 1) ? q0[ch >> 1].y : q0[ch >> 1].x;
    unsigned long long qw1 = (ch & 1) ? q1[ch >> 1].y : q1[ch >> 1].x;
    const unsigned short* tb = (const unsigned short*)&Tb[buf][0];
    #pragma unroll
    for (int cl = 0; cl < 8; ++cl) {
      int c0 = (int)(qw0 >> (8 * cl)) & 255;
      int c1 = (int)(qw1 >> (8 * cl)) & 255;
      union { unsigned int u[4]; bf16x8 v; } A0, A1;
      unsigned s0 = 0x3F80u << ((c0 & 1) << 4);     // bf16(1.0) in right half
      unsigned s1 = 0x3F80u << ((c1 & 1) << 4);
      int p0 = c0 >> 1, p1 = c1 >> 1;
      #pragma unroll
      for (int j = 0; j < 4; ++j) {
        A0.u[j] = (p0 == h * 4 + j) ? s0 : 0u;
        A1.u[j] = (p1 == h * 4 + j) ? s1 : 0u;
      }
      #pragma unroll
      for (int ct = 0; ct < 2; ++ct) {
        int col = cq * 64 + ct * 32 + lrow;
        unsigned uidx = (unsigned)(cl * 2048)
                      + (((unsigned)(col * 16 + h * 8))
                         ^ ((((unsigned)col >> 2) & 7u) << 3));
        bf16x8 bv = *(const bf16x8*)(tb + uidx);    // swizzled, conflict-free
        acc[0][ct] = __builtin_amdgcn_mfma_f32_32x32x16_bf16(A0.v, bv, acc[0][ct], 0, 0, 0);
        acc[1][ct] = __builtin_amdgcn_mfma_f32_32x32x16_bf16(A1.v, bv, acc[1][ct], 0, 0, 0);
      }
    }
    __syncthreads();   // compiler drains vmcnt here -> stage(ch+1) complete
  }

  // epilogue: D layout col=lane&31, row=(reg&3)+8*(reg>>2)+4*(lane>>5)
  float bval[2];
  #pragma unroll
  for (int ct = 0; ct < 2; ++ct) bval[ct] = bias[g * 128 + cq * 64 + ct * 32 + lrow];
  #pragma unroll
  for (int rt = 0; rt < 2; ++rt)
    #pragma unroll
    for (int ct = 0; ct < 2; ++ct) {
      int col = g * 128 + cq * 64 + ct * 32 + lrow;
      #pragma unroll
      for (int r = 0; r < 16; ++r) {
        int row = n0 + rq * 64 + rt * 32 + (r & 3) + 8 * (r >> 2) + 4 * h;
        out[(size_t)row * DOUTN + col] = acc[rt][ct][r] + bval[ct];
      }
    }
}

extern "C" void kernel_launch(void* const* d_in, const int* in_sizes, int n_in,
                              void* d_out, int out_size, void* d_ws, size_t ws_size,
                              hipStream_t stream) {
  const float* x    = (const float*)d_in[0];
  const int*   sidx = (const int*)d_in[1];
  const float* sval = (const float*)d_in[2];
  const float* Tg   = (const float*)d_in[3];
  const float* bias = (const float*)d_in[4];
  float* out = (float*)d_out;
  unsigned char* codes = (unsigned char*)d_ws;                       // 1 MiB
  unsigned int*  Tswz  = (unsigned int*)((char*)d_ws + (1 << 20));   // 2 MiB

  prep_k<<<NN / 8 + 64, 256, 0, stream>>>(x, sidx, sval, Tg, codes, Tswz);
  maddness_mfma<<<dim3(8, 128), 256, 0, stream>>>(Tswz, bias, codes, out);
}